// Round 1
// baseline (316.732 us; speedup 1.0000x reference)
//
#include <hip/hip_runtime.h>

#define S_SCALE 11.313708498984761f
#define EPS 1e-12f

typedef __bf16 bf16x8 __attribute__((ext_vector_type(8)));
typedef float  f32x4  __attribute__((ext_vector_type(4)));

__device__ __forceinline__ f32x4 mfma16(bf16x8 a, bf16x8 b, f32x4 c) {
  return __builtin_amdgcn_mfma_f32_16x16x32_bf16(a, b, c, 0, 0, 0);
}

__device__ __forceinline__ float waveSum(float v) {
#pragma unroll
  for (int m = 32; m > 0; m >>= 1) v += __shfl_xor(v, m, 64);
  return v;
}

// ---- ws layout (byte offsets) ----
// W bf16 [128][3072]       : [0, 786432)
// bias2 f32 [128]          : [786432, 786944)
// fn bf16 [8192][128]      : [786944, 2884096)
// Z1 f32 [32][256]         : [2884096, 2916864)
// Z2 f32 [32][256]         : [2916864, 2949632)   (Z1,Z2 contiguous: 16384 floats)
// Wtmp4 f32 [4][128][3072] : [2949632, 9241088)
#define OFF_W    0
#define OFF_BIAS 786432
#define OFF_FN   786944
#define OFF_Z1   2884096
#define OFF_Z2   2916864
#define OFF_WTMP 2949632

// ---------------- init: zero Z1,Z2 and loss slot ----------------
__global__ void k_init(float* __restrict__ Z, float* __restrict__ loss) {
  int idx = blockIdx.x * 256 + threadIdx.x;
  if (idx < 16384) Z[idx] = 0.f;
  if (idx == 0) loss[0] = 0.f;
}

// ---------------- fused bias: bias2[o] = fc1_w[o,:] . conv_b + fc1_b[o] -----
__global__ __launch_bounds__(256) void k_bias(const float* __restrict__ fc1_w,
                                              const float* __restrict__ conv_b,
                                              const float* __restrict__ fc1_b,
                                              float* __restrict__ bias2) {
  const int o = blockIdx.x, t = threadIdx.x;
  float p = fc1_w[o * 512 + t] * conv_b[t] +
            fc1_w[o * 512 + 256 + t] * conv_b[256 + t];
  p = waveSum(p);
  __shared__ float red[4];
  if ((t & 63) == 0) red[t >> 6] = p;
  __syncthreads();
  if (t == 0) bias2[o] = red[0] + red[1] + red[2] + red[3] + fc1_b[o];
}

// ---------------- fused weight partials: Wtmp[cs][o][k] = sum_c fc1*conv_w --
__global__ __launch_bounds__(256) void k_fusew(const float* __restrict__ conv_w,
                                               const float* __restrict__ fc1_w,
                                               float* __restrict__ Wtmp) {
  __shared__ float cw_s[64][36];    // [c][k], padded
  __shared__ float fc1_s[128][65];  // [o][c], padded
  const int t = threadIdx.x;
  const int kt = blockIdx.x, cs = blockIdx.y;
  const int k0 = kt * 32;
  const int og = t >> 3, kg = t & 7;  // thread tile: 4 o x 4 k
  float acc[4][4] = {};
  for (int half = 0; half < 2; ++half) {
    const int cc = cs * 128 + half * 64;
    __syncthreads();
#pragma unroll
    for (int i = 0; i < 8; ++i) {
      int idx = t + 256 * i;
      int cr = idx >> 5, kk = idx & 31;
      cw_s[cr][kk] = conv_w[(cc + cr) * 3072 + k0 + kk];
    }
#pragma unroll
    for (int i = 0; i < 8; ++i) {
      int idx = t + 256 * i;
      int o = idx >> 4, c4 = (idx & 15) * 4;
      float4 v = *(const float4*)&fc1_w[o * 512 + cc + c4];
      fc1_s[o][c4 + 0] = v.x; fc1_s[o][c4 + 1] = v.y;
      fc1_s[o][c4 + 2] = v.z; fc1_s[o][c4 + 3] = v.w;
    }
    __syncthreads();
    for (int ci = 0; ci < 64; ++ci) {
      float4 cw = *(const float4*)&cw_s[ci][kg * 4];
#pragma unroll
      for (int j = 0; j < 4; ++j) {
        float fv = fc1_s[og * 4 + j][ci];
        acc[j][0] = fmaf(fv, cw.x, acc[j][0]);
        acc[j][1] = fmaf(fv, cw.y, acc[j][1]);
        acc[j][2] = fmaf(fv, cw.z, acc[j][2]);
        acc[j][3] = fmaf(fv, cw.w, acc[j][3]);
      }
    }
  }
  float* wp = Wtmp + cs * 393216;
#pragma unroll
  for (int j = 0; j < 4; ++j)
#pragma unroll
    for (int q = 0; q < 4; ++q)
      wp[(og * 4 + j) * 3072 + k0 + kg * 4 + q] = acc[j][q];
}

// ---------------- reduce 4 partials -> bf16 W ----------------
__global__ void k_cvtw(const float* __restrict__ Wtmp, __bf16* __restrict__ W) {
  int idx = blockIdx.x * 256 + threadIdx.x;
  float s = Wtmp[idx] + Wtmp[idx + 393216] + Wtmp[idx + 786432] +
            Wtmp[idx + 1179648];
  W[idx] = (__bf16)s;
}

// ---------------- main fused GEMM: f[8192,128] = x[8192,3072] @ W^T + b ----
__global__ __launch_bounds__(256) void k_gemm1(const float* __restrict__ x,
                                               const __bf16* __restrict__ W,
                                               const float* __restrict__ bias2,
                                               float* __restrict__ f) {
  __shared__ __align__(16) __bf16 As[16][72];
  __shared__ __align__(16) __bf16 Bs[128][72];
  const int t = threadIdx.x;
  const int m0 = blockIdx.x * 16;
  const int wave = t >> 6, lane = t & 63;
  const int l15 = lane & 15, quad = lane >> 4;
  const int wn = wave * 32;
  const int ar_r = t >> 4, ar_c = (t & 15) * 4;
  const int br_r = t >> 3, br_c = (t & 7) * 8;

  f32x4 acc0 = {0.f, 0.f, 0.f, 0.f}, acc1 = {0.f, 0.f, 0.f, 0.f};
  float4 areg;
  uint4 breg[4];
  areg = *(const float4*)&x[(m0 + ar_r) * 3072 + ar_c];
#pragma unroll
  for (int i = 0; i < 4; ++i)
    breg[i] = *(const uint4*)&W[(br_r + 32 * i) * 3072 + br_c];

  for (int kt = 0; kt < 48; ++kt) {
    __syncthreads();
    {
      union { __bf16 h[4]; unsigned long long u; } pk;
      pk.h[0] = (__bf16)areg.x; pk.h[1] = (__bf16)areg.y;
      pk.h[2] = (__bf16)areg.z; pk.h[3] = (__bf16)areg.w;
      *(unsigned long long*)&As[ar_r][ar_c] = pk.u;
#pragma unroll
      for (int i = 0; i < 4; ++i)
        *(uint4*)&Bs[br_r + 32 * i][br_c] = breg[i];
    }
    __syncthreads();
    if (kt + 1 < 48) {  // prefetch next tiles; latency hidden behind MFMAs
      int k0 = (kt + 1) * 64;
      areg = *(const float4*)&x[(m0 + ar_r) * 3072 + k0 + ar_c];
#pragma unroll
      for (int i = 0; i < 4; ++i)
        breg[i] = *(const uint4*)&W[(br_r + 32 * i) * 3072 + k0 + br_c];
    }
#pragma unroll
    for (int ks = 0; ks < 2; ++ks) {
      bf16x8 af = *(const bf16x8*)&As[l15][ks * 32 + quad * 8];
      bf16x8 b0 = *(const bf16x8*)&Bs[wn + l15][ks * 32 + quad * 8];
      bf16x8 b1 = *(const bf16x8*)&Bs[wn + 16 + l15][ks * 32 + quad * 8];
      acc0 = mfma16(af, b0, acc0);
      acc1 = mfma16(af, b1, acc1);
    }
  }
#pragma unroll
  for (int nt = 0; nt < 2; ++nt) {
    f32x4 a = nt ? acc1 : acc0;
    int col = wn + nt * 16 + l15;
    float bv = bias2[col];
#pragma unroll
    for (int r = 0; r < 4; ++r) {
      int row = m0 + quad * 4 + r;
      f[row * 128 + col] = a[r] + bv;
    }
  }
}

// ---------------- row L2-norms -> fn bf16 ----------------
__global__ __launch_bounds__(256) void k_norm(const float* __restrict__ f,
                                              __bf16* __restrict__ fn) {
  const int wave = threadIdx.x >> 6, lane = threadIdx.x & 63;
  const int row = blockIdx.x * 4 + wave;
  float a = f[row * 128 + lane];
  float c = f[row * 128 + 64 + lane];
  float ss = waveSum(fmaf(a, a, c * c));
  float inv = 1.f / fmaxf(sqrtf(ss), EPS);
  fn[row * 128 + lane] = (__bf16)(a * inv);
  fn[row * 128 + 64 + lane] = (__bf16)(c * inv);
}

// ---------------- A[b] = fn_b @ fn_b^T (symmetric cosine affinity) ---------
__global__ __launch_bounds__(256) void k_gemm2(const __bf16* __restrict__ fn,
                                               float* __restrict__ Aout) {
  __shared__ __align__(16) __bf16 Li[64][136];
  __shared__ __align__(16) __bf16 Lj[64][136];
  const int t = threadIdx.x;
  const int b = blockIdx.y;
  const int ti = blockIdx.x >> 2, tj = blockIdx.x & 3;
  const int i0 = ti * 64, j0 = tj * 64;
  const int wave = t >> 6, lane = t & 63;
  const int l15 = lane & 15, quad = lane >> 4;
  const __bf16* fb = fn + b * 32768;
#pragma unroll
  for (int i = 0; i < 4; ++i) {
    int idx = t + 256 * i;
    int r = idx >> 4, c8 = (idx & 15) * 8;
    *(uint4*)&Li[r][c8] = *(const uint4*)&fb[(i0 + r) * 128 + c8];
    *(uint4*)&Lj[r][c8] = *(const uint4*)&fb[(j0 + r) * 128 + c8];
  }
  __syncthreads();
  f32x4 acc[4] = {{0.f, 0.f, 0.f, 0.f}, {0.f, 0.f, 0.f, 0.f},
                  {0.f, 0.f, 0.f, 0.f}, {0.f, 0.f, 0.f, 0.f}};
#pragma unroll
  for (int ks = 0; ks < 4; ++ks) {
    bf16x8 af = *(const bf16x8*)&Li[wave * 16 + l15][ks * 32 + quad * 8];
#pragma unroll
    for (int nt = 0; nt < 4; ++nt) {
      bf16x8 bf = *(const bf16x8*)&Lj[nt * 16 + l15][ks * 32 + quad * 8];
      acc[nt] = mfma16(af, bf, acc[nt]);
    }
  }
  float* Ab = Aout + b * 65536;
#pragma unroll
  for (int nt = 0; nt < 4; ++nt) {
    int gj = j0 + nt * 16 + l15;
#pragma unroll
    for (int r = 0; r < 4; ++r) {
      int gi = i0 + wave * 16 + quad * 4 + r;
      Ab[gi * 256 + gj] = acc[nt][r];
    }
  }
}

// ---------------- Z1/Z2: column sums of E*mask*drop ----------------
// E[n,m] = exp(s*(A[n,m]-1)); softmax denom + shift cancel under L1-renorm.
__global__ __launch_bounds__(256) void k_z(const float* __restrict__ Aout,
                                           const float* __restrict__ d1,
                                           const float* __restrict__ d2,
                                           float* __restrict__ Z1,
                                           float* __restrict__ Z2) {
  const int t = threadIdx.x;  // column m
  const int b = blockIdx.y, nc = blockIdx.x;
  const int base = b * 65536;
  float z1 = 0.f, z2 = 0.f;
  for (int r = 0; r < 32; ++r) {
    int n = nc * 32 + r;
    int idx = base + n * 256 + t;
    float a = Aout[idx];
    float e = __expf(fmaf(S_SCALE, a, -S_SCALE));
    if (n != t) {
      z1 = fmaf(e, d1[idx], z1);
      z2 = fmaf(e, d2[idx], z2);
    }
  }
  atomicAdd(&Z1[b * 256 + t], z1);
  atomicAdd(&Z2[b * 256 + t], z2);
}

// ---------------- loss = -1/8192 * sum E^2*d2[i,k]*d1[k,i]/(Z2[k]Z1[i]) ----
__global__ __launch_bounds__(256) void k_loss(const float* __restrict__ Aout,
                                              const float* __restrict__ d1,
                                              const float* __restrict__ d2,
                                              const float* __restrict__ Z1,
                                              const float* __restrict__ Z2,
                                              float* __restrict__ loss) {
  __shared__ float d1s[64][65];  // d1[k][i] tile, transposed access
  __shared__ float red[4];
  const int t = threadIdx.x;
  const int b = blockIdx.y;
  const int ic = blockIdx.x >> 2, kc = blockIdx.x & 3;
  const int i0 = ic * 64, k0 = kc * 64;
  const int base = b * 65536;
#pragma unroll
  for (int ii = 0; ii < 16; ++ii) {
    int idx = t + 256 * ii;
    int kr = idx >> 6, ci = idx & 63;
    d1s[kr][ci] = d1[base + (k0 + kr) * 256 + i0 + ci];
  }
  __syncthreads();
  const int kl = t & 63, ig = t >> 6;
  float inv2 = 1.f / fmaxf(Z2[b * 256 + k0 + kl], EPS);
  float accv = 0.f;
  for (int ii = 0; ii < 16; ++ii) {
    int il = ig * 16 + ii;
    float inv1 = 1.f / fmaxf(Z1[b * 256 + i0 + il], EPS);
    int idx = base + (i0 + il) * 256 + k0 + kl;
    float a = Aout[idx];
    float e = __expf(fmaf(2.f * S_SCALE, a, -2.f * S_SCALE));
    float v = e * d2[idx] * d1s[kl][il] * inv1 * inv2;
    if (i0 + il != k0 + kl) accv += v;
  }
  accv = waveSum(accv);
  if ((t & 63) == 0) red[t >> 6] = accv;
  __syncthreads();
  if (t == 0) {
    float tot = red[0] + red[1] + red[2] + red[3];
    atomicAdd(loss, tot * (-1.f / 8192.f));
  }
}

extern "C" void kernel_launch(void* const* d_in, const int* in_sizes, int n_in,
                              void* d_out, int out_size, void* d_ws,
                              size_t ws_size, hipStream_t stream) {
  const float* x = (const float*)d_in[0];
  const float* conv_w = (const float*)d_in[1];
  const float* conv_b = (const float*)d_in[2];
  const float* fc1_w = (const float*)d_in[3];
  const float* fc1_b = (const float*)d_in[4];
  const float* drop1 = (const float*)d_in[5];
  const float* drop2 = (const float*)d_in[6];
  char* ws = (char*)d_ws;
  __bf16* W = (__bf16*)(ws + OFF_W);
  float* bias2 = (float*)(ws + OFF_BIAS);
  __bf16* fn = (__bf16*)(ws + OFF_FN);
  float* Z1 = (float*)(ws + OFF_Z1);
  float* Z2 = (float*)(ws + OFF_Z2);
  float* Wtmp = (float*)(ws + OFF_WTMP);
  float* f = (float*)d_out;         // [8192,128]
  float* Aout = f + 1048576;        // [32,256,256]
  float* loss = f + 3145728;        // scalar

  k_init<<<64, 256, 0, stream>>>(Z1, loss);
  k_bias<<<128, 256, 0, stream>>>(fc1_w, conv_b, fc1_b, bias2);
  k_fusew<<<dim3(96, 4), 256, 0, stream>>>(conv_w, fc1_w, Wtmp);
  k_cvtw<<<1536, 256, 0, stream>>>(Wtmp, W);
  k_gemm1<<<512, 256, 0, stream>>>(x, W, bias2, f);
  k_norm<<<2048, 256, 0, stream>>>(f, fn);
  k_gemm2<<<dim3(16, 32), 256, 0, stream>>>(fn, Aout);
  k_z<<<dim3(8, 32), 256, 0, stream>>>(Aout, drop1, drop2, Z1, Z2);
  k_loss<<<dim3(16, 32), 256, 0, stream>>>(Aout, drop1, drop2, Z1, Z2, loss);
}

// Round 2
// 291.274 us; speedup vs baseline: 1.0874x; 1.0874x over previous
//
#include <hip/hip_runtime.h>

#define S_SCALE 11.313708498984761f
#define EPS 1e-12f

typedef __bf16 bf16x8 __attribute__((ext_vector_type(8)));
typedef float  f32x4  __attribute__((ext_vector_type(4)));

__device__ __forceinline__ f32x4 mfma16(bf16x8 a, bf16x8 b, f32x4 c) {
  return __builtin_amdgcn_mfma_f32_16x16x32_bf16(a, b, c, 0, 0, 0);
}

__device__ __forceinline__ float waveSum(float v) {
#pragma unroll
  for (int m = 32; m > 0; m >>= 1) v += __shfl_xor(v, m, 64);
  return v;
}

// ---- ws layout (byte offsets) ----
#define OFF_W    0
#define OFF_BIAS 786432
#define OFF_FN   786944
#define OFF_Z1   2884096
#define OFF_Z2   2916864
#define OFF_WTMP 2949632

// ---------------- init: zero f (atomic target), Z1,Z2, loss ----------------
__global__ void k_init(float* __restrict__ f, float* __restrict__ Z,
                       float* __restrict__ loss) {
  int idx = blockIdx.x * 256 + threadIdx.x;
  if (idx < 1048576) f[idx] = 0.f;
  if (idx < 16384) Z[idx] = 0.f;
  if (idx == 0) loss[0] = 0.f;
}

// ---------------- fused bias: bias2[o] = fc1_w[o,:] . conv_b + fc1_b[o] -----
__global__ __launch_bounds__(256) void k_bias(const float* __restrict__ fc1_w,
                                              const float* __restrict__ conv_b,
                                              const float* __restrict__ fc1_b,
                                              float* __restrict__ bias2) {
  const int o = blockIdx.x, t = threadIdx.x;
  float p = fc1_w[o * 512 + t] * conv_b[t] +
            fc1_w[o * 512 + 256 + t] * conv_b[256 + t];
  p = waveSum(p);
  __shared__ float red[4];
  if ((t & 63) == 0) red[t >> 6] = p;
  __syncthreads();
  if (t == 0) bias2[o] = red[0] + red[1] + red[2] + red[3] + fc1_b[o];
}

// ---------------- fused weight partials: Wtmp[cs][o][k] = sum_c fc1*conv_w --
__global__ __launch_bounds__(256) void k_fusew(const float* __restrict__ conv_w,
                                               const float* __restrict__ fc1_w,
                                               float* __restrict__ Wtmp) {
  __shared__ float cw_s[64][36];    // [c][k], padded
  __shared__ float fc1_s[128][65];  // [o][c], padded
  const int t = threadIdx.x;
  const int kt = blockIdx.x, cs = blockIdx.y;
  const int k0 = kt * 32;
  const int og = t >> 3, kg = t & 7;  // thread tile: 4 o x 4 k
  float acc[4][4] = {};
  for (int half = 0; half < 2; ++half) {
    const int cc = cs * 128 + half * 64;
    __syncthreads();
#pragma unroll
    for (int i = 0; i < 8; ++i) {
      int idx = t + 256 * i;
      int cr = idx >> 5, kk = idx & 31;
      cw_s[cr][kk] = conv_w[(cc + cr) * 3072 + k0 + kk];
    }
#pragma unroll
    for (int i = 0; i < 8; ++i) {
      int idx = t + 256 * i;
      int o = idx >> 4, c4 = (idx & 15) * 4;
      float4 v = *(const float4*)&fc1_w[o * 512 + cc + c4];
      fc1_s[o][c4 + 0] = v.x; fc1_s[o][c4 + 1] = v.y;
      fc1_s[o][c4 + 2] = v.z; fc1_s[o][c4 + 3] = v.w;
    }
    __syncthreads();
    for (int ci = 0; ci < 64; ++ci) {
      float4 cw = *(const float4*)&cw_s[ci][kg * 4];
#pragma unroll
      for (int j = 0; j < 4; ++j) {
        float fv = fc1_s[og * 4 + j][ci];
        acc[j][0] = fmaf(fv, cw.x, acc[j][0]);
        acc[j][1] = fmaf(fv, cw.y, acc[j][1]);
        acc[j][2] = fmaf(fv, cw.z, acc[j][2]);
        acc[j][3] = fmaf(fv, cw.w, acc[j][3]);
      }
    }
  }
  float* wp = Wtmp + cs * 393216;
#pragma unroll
  for (int j = 0; j < 4; ++j)
#pragma unroll
    for (int q = 0; q < 4; ++q)
      wp[(og * 4 + j) * 3072 + k0 + kg * 4 + q] = acc[j][q];
}

// ---------------- reduce 4 partials -> bf16 W ----------------
__global__ void k_cvtw(const float* __restrict__ Wtmp, __bf16* __restrict__ W) {
  int idx = blockIdx.x * 256 + threadIdx.x;
  float s = Wtmp[idx] + Wtmp[idx + 393216] + Wtmp[idx + 786432] +
            Wtmp[idx + 1179648];
  W[idx] = (__bf16)s;
}

// ---------------- main fused GEMM, split-K: f += x_chunk @ W_chunk^T -------
// grid (256, 4): x = M-tile of 32 rows, y = K-split (768 per split).
__global__ __launch_bounds__(256) void k_gemm1(const float* __restrict__ x,
                                               const __bf16* __restrict__ W,
                                               const float* __restrict__ bias2,
                                               float* __restrict__ f) {
  __shared__ __align__(16) __bf16 As[32][72];
  __shared__ __align__(16) __bf16 Bs[128][72];
  const int t = threadIdx.x;
  const int m0 = blockIdx.x * 32;
  const int kbase = blockIdx.y * 768;
  const int wave = t >> 6, lane = t & 63;
  const int l15 = lane & 15, quad = lane >> 4;
  const int ar = t >> 3, ac = (t & 7) * 8;  // A stage: 32 rows x 64 cols
  const int br = t >> 3, bc = (t & 7) * 8;  // B stage: rows br+32i

  f32x4 acc[2][2] = {{{0.f,0.f,0.f,0.f},{0.f,0.f,0.f,0.f}},
                     {{0.f,0.f,0.f,0.f},{0.f,0.f,0.f,0.f}}};
  float4 a0, a1;
  uint4 breg[4];
  const float* xp = x + (m0 + ar) * 3072 + kbase + ac;
  a0 = *(const float4*)xp;
  a1 = *(const float4*)(xp + 4);
#pragma unroll
  for (int i = 0; i < 4; ++i)
    breg[i] = *(const uint4*)&W[(br + 32 * i) * 3072 + kbase + bc];

  for (int kt = 0; kt < 12; ++kt) {
    __syncthreads();
    {
      union { __bf16 h[8]; uint4 u; } pk;
      pk.h[0] = (__bf16)a0.x; pk.h[1] = (__bf16)a0.y;
      pk.h[2] = (__bf16)a0.z; pk.h[3] = (__bf16)a0.w;
      pk.h[4] = (__bf16)a1.x; pk.h[5] = (__bf16)a1.y;
      pk.h[6] = (__bf16)a1.z; pk.h[7] = (__bf16)a1.w;
      *(uint4*)&As[ar][ac] = pk.u;
#pragma unroll
      for (int i = 0; i < 4; ++i)
        *(uint4*)&Bs[br + 32 * i][bc] = breg[i];
    }
    __syncthreads();
    if (kt + 1 < 12) {  // register prefetch; latency hidden behind MFMAs
      const float* xn = xp + (kt + 1) * 64;
      a0 = *(const float4*)xn;
      a1 = *(const float4*)(xn + 4);
      int k0 = kbase + (kt + 1) * 64;
#pragma unroll
      for (int i = 0; i < 4; ++i)
        breg[i] = *(const uint4*)&W[(br + 32 * i) * 3072 + k0 + bc];
    }
#pragma unroll
    for (int ks = 0; ks < 2; ++ks) {
      bf16x8 af0 = *(const bf16x8*)&As[l15][ks * 32 + quad * 8];
      bf16x8 af1 = *(const bf16x8*)&As[16 + l15][ks * 32 + quad * 8];
      bf16x8 bf0 = *(const bf16x8*)&Bs[wave * 32 + l15][ks * 32 + quad * 8];
      bf16x8 bf1 = *(const bf16x8*)&Bs[wave * 32 + 16 + l15][ks * 32 + quad * 8];
      acc[0][0] = mfma16(af0, bf0, acc[0][0]);
      acc[0][1] = mfma16(af0, bf1, acc[0][1]);
      acc[1][0] = mfma16(af1, bf0, acc[1][0]);
      acc[1][1] = mfma16(af1, bf1, acc[1][1]);
    }
  }
  const bool add_bias = (blockIdx.y == 0);
#pragma unroll
  for (int mi = 0; mi < 2; ++mi)
#pragma unroll
    for (int ni = 0; ni < 2; ++ni) {
      int col = wave * 32 + ni * 16 + l15;
      float bv = add_bias ? bias2[col] : 0.f;
#pragma unroll
      for (int r = 0; r < 4; ++r) {
        int row = m0 + mi * 16 + quad * 4 + r;
        atomicAdd(&f[row * 128 + col], acc[mi][ni][r] + bv * 0.25f);
      }
    }
}

// ---------------- row L2-norms -> fn bf16 ----------------
__global__ __launch_bounds__(256) void k_norm(const float* __restrict__ f,
                                              __bf16* __restrict__ fn) {
  const int wave = threadIdx.x >> 6, lane = threadIdx.x & 63;
  const int row = blockIdx.x * 4 + wave;
  float a = f[row * 128 + lane];
  float c = f[row * 128 + 64 + lane];
  float ss = waveSum(fmaf(a, a, c * c));
  float inv = 1.f / fmaxf(sqrtf(ss), EPS);
  fn[row * 128 + lane] = (__bf16)(a * inv);
  fn[row * 128 + 64 + lane] = (__bf16)(c * inv);
}

// ---------------- A[b] = fn_b @ fn_b^T (symmetric cosine affinity) ---------
__global__ __launch_bounds__(256) void k_gemm2(const __bf16* __restrict__ fn,
                                               float* __restrict__ Aout) {
  __shared__ __align__(16) __bf16 Li[64][136];
  __shared__ __align__(16) __bf16 Lj[64][136];
  const int t = threadIdx.x;
  const int b = blockIdx.y;
  const int ti = blockIdx.x >> 2, tj = blockIdx.x & 3;
  const int i0 = ti * 64, j0 = tj * 64;
  const int wave = t >> 6, lane = t & 63;
  const int l15 = lane & 15, quad = lane >> 4;
  const __bf16* fb = fn + b * 32768;
#pragma unroll
  for (int i = 0; i < 4; ++i) {
    int idx = t + 256 * i;
    int r = idx >> 4, c8 = (idx & 15) * 8;
    *(uint4*)&Li[r][c8] = *(const uint4*)&fb[(i0 + r) * 128 + c8];
    *(uint4*)&Lj[r][c8] = *(const uint4*)&fb[(j0 + r) * 128 + c8];
  }
  __syncthreads();
  f32x4 acc[4] = {{0.f, 0.f, 0.f, 0.f}, {0.f, 0.f, 0.f, 0.f},
                  {0.f, 0.f, 0.f, 0.f}, {0.f, 0.f, 0.f, 0.f}};
#pragma unroll
  for (int ks = 0; ks < 4; ++ks) {
    bf16x8 af = *(const bf16x8*)&Li[wave * 16 + l15][ks * 32 + quad * 8];
#pragma unroll
    for (int nt = 0; nt < 4; ++nt) {
      bf16x8 bf = *(const bf16x8*)&Lj[nt * 16 + l15][ks * 32 + quad * 8];
      acc[nt] = mfma16(af, bf, acc[nt]);
    }
  }
  float* Ab = Aout + b * 65536;
#pragma unroll
  for (int nt = 0; nt < 4; ++nt) {
    int gj = j0 + nt * 16 + l15;
#pragma unroll
    for (int r = 0; r < 4; ++r) {
      int gi = i0 + wave * 16 + quad * 4 + r;
      Ab[gi * 256 + gj] = acc[nt][r];
    }
  }
}

// ---------------- Z1/Z2: column sums of E*mask*drop ----------------
// E[n,m] = exp(s*(A[n,m]-1)); softmax denom + shift cancel under L1-renorm.
__global__ __launch_bounds__(256) void k_z(const float* __restrict__ Aout,
                                           const float* __restrict__ d1,
                                           const float* __restrict__ d2,
                                           float* __restrict__ Z1,
                                           float* __restrict__ Z2) {
  const int t = threadIdx.x;  // column m
  const int b = blockIdx.y, nc = blockIdx.x;
  const int base = b * 65536;
  float z1 = 0.f, z2 = 0.f;
  for (int r = 0; r < 32; ++r) {
    int n = nc * 32 + r;
    int idx = base + n * 256 + t;
    float a = Aout[idx];
    float e = __expf(fmaf(S_SCALE, a, -S_SCALE));
    if (n != t) {
      z1 = fmaf(e, d1[idx], z1);
      z2 = fmaf(e, d2[idx], z2);
    }
  }
  atomicAdd(&Z1[b * 256 + t], z1);
  atomicAdd(&Z2[b * 256 + t], z2);
}

// ---------------- loss = -1/8192 * sum E^2*d2[i,k]*d1[k,i]/(Z2[k]Z1[i]) ----
__global__ __launch_bounds__(256) void k_loss(const float* __restrict__ Aout,
                                              const float* __restrict__ d1,
                                              const float* __restrict__ d2,
                                              const float* __restrict__ Z1,
                                              const float* __restrict__ Z2,
                                              float* __restrict__ loss) {
  __shared__ float d1s[64][65];  // d1[k][i] tile, transposed access
  __shared__ float red[4];
  const int t = threadIdx.x;
  const int b = blockIdx.y;
  const int ic = blockIdx.x >> 2, kc = blockIdx.x & 3;
  const int i0 = ic * 64, k0 = kc * 64;
  const int base = b * 65536;
#pragma unroll
  for (int ii = 0; ii < 16; ++ii) {
    int idx = t + 256 * ii;
    int kr = idx >> 6, ci = idx & 63;
    d1s[kr][ci] = d1[base + (k0 + kr) * 256 + i0 + ci];
  }
  __syncthreads();
  const int kl = t & 63, ig = t >> 6;
  float inv2 = 1.f / fmaxf(Z2[b * 256 + k0 + kl], EPS);
  float accv = 0.f;
  for (int ii = 0; ii < 16; ++ii) {
    int il = ig * 16 + ii;
    float inv1 = 1.f / fmaxf(Z1[b * 256 + i0 + il], EPS);
    int idx = base + (i0 + il) * 256 + k0 + kl;
    float a = Aout[idx];
    float e = __expf(fmaf(2.f * S_SCALE, a, -2.f * S_SCALE));
    float v = e * d2[idx] * d1s[kl][il] * inv1 * inv2;
    if (i0 + il != k0 + kl) accv += v;
  }
  accv = waveSum(accv);
  if ((t & 63) == 0) red[t >> 6] = accv;
  __syncthreads();
  if (t == 0) {
    float tot = red[0] + red[1] + red[2] + red[3];
    atomicAdd(loss, tot * (-1.f / 8192.f));
  }
}

extern "C" void kernel_launch(void* const* d_in, const int* in_sizes, int n_in,
                              void* d_out, int out_size, void* d_ws,
                              size_t ws_size, hipStream_t stream) {
  const float* x = (const float*)d_in[0];
  const float* conv_w = (const float*)d_in[1];
  const float* conv_b = (const float*)d_in[2];
  const float* fc1_w = (const float*)d_in[3];
  const float* fc1_b = (const float*)d_in[4];
  const float* drop1 = (const float*)d_in[5];
  const float* drop2 = (const float*)d_in[6];
  char* ws = (char*)d_ws;
  __bf16* W = (__bf16*)(ws + OFF_W);
  float* bias2 = (float*)(ws + OFF_BIAS);
  __bf16* fn = (__bf16*)(ws + OFF_FN);
  float* Z1 = (float*)(ws + OFF_Z1);
  float* Z2 = (float*)(ws + OFF_Z2);
  float* Wtmp = (float*)(ws + OFF_WTMP);
  float* f = (float*)d_out;         // [8192,128]
  float* Aout = f + 1048576;        // [32,256,256]
  float* loss = f + 3145728;        // scalar

  k_init<<<4096, 256, 0, stream>>>(f, Z1, loss);
  k_bias<<<128, 256, 0, stream>>>(fc1_w, conv_b, fc1_b, bias2);
  k_fusew<<<dim3(96, 4), 256, 0, stream>>>(conv_w, fc1_w, Wtmp);
  k_cvtw<<<1536, 256, 0, stream>>>(Wtmp, W);
  k_gemm1<<<dim3(256, 4), 256, 0, stream>>>(x, W, bias2, f);
  k_norm<<<2048, 256, 0, stream>>>(f, fn);
  k_gemm2<<<dim3(16, 32), 256, 0, stream>>>(fn, Aout);
  k_z<<<dim3(8, 32), 256, 0, stream>>>(Aout, drop1, drop2, Z1, Z2);
  k_loss<<<dim3(16, 32), 256, 0, stream>>>(Aout, drop1, drop2, Z1, Z2, loss);
}

// Round 3
// 285.764 us; speedup vs baseline: 1.1084x; 1.0193x over previous
//
#include <hip/hip_runtime.h>

#define S_SCALE 11.313708498984761f
#define EPS 1e-12f

typedef __bf16 bf16x8 __attribute__((ext_vector_type(8)));
typedef float  f32x4  __attribute__((ext_vector_type(4)));

__device__ __forceinline__ f32x4 mfma16(bf16x8 a, bf16x8 b, f32x4 c) {
  return __builtin_amdgcn_mfma_f32_16x16x32_bf16(a, b, c, 0, 0, 0);
}

__device__ __forceinline__ float waveSum(float v) {
#pragma unroll
  for (int m = 32; m > 0; m >>= 1) v += __shfl_xor(v, m, 64);
  return v;
}

// ---- ws layout (byte offsets) ----
// W bf16 [128][3072]        : [0, 786432)
// bias2 f32 [128]           : [786432, 786944)
// fn bf16 [8192][128]       : [786944, 2884096)
// Zp f32 [2][8][32][256]    : [2884096, 3408384)   (overlaps Wtmp; Wtmp dead first)
// Wtmp f32 [4][128][3072]   : [2884096, 9175552)
#define OFF_W    0
#define OFF_BIAS 786432
#define OFF_FN   786944
#define OFF_ZP   2884096
#define OFF_WTMP 2884096

// ---------------- fused bias: bias2[o] = fc1_w[o,:] . conv_b + fc1_b[o] ----
// also zeroes the loss accumulator (runs first on the stream).
__global__ __launch_bounds__(256) void k_bias(const float* __restrict__ fc1_w,
                                              const float* __restrict__ conv_b,
                                              const float* __restrict__ fc1_b,
                                              float* __restrict__ bias2,
                                              float* __restrict__ loss) {
  const int o = blockIdx.x, t = threadIdx.x;
  if (o == 0 && t == 0) loss[0] = 0.f;
  float p = fc1_w[o * 512 + t] * conv_b[t] +
            fc1_w[o * 512 + 256 + t] * conv_b[256 + t];
  p = waveSum(p);
  __shared__ float red[4];
  if ((t & 63) == 0) red[t >> 6] = p;
  __syncthreads();
  if (t == 0) bias2[o] = red[0] + red[1] + red[2] + red[3] + fc1_b[o];
}

// ---------------- fused weight partials: Wtmp[cs][o][k] = sum_c fc1*conv_w --
__global__ __launch_bounds__(256) void k_fusew(const float* __restrict__ conv_w,
                                               const float* __restrict__ fc1_w,
                                               float* __restrict__ Wtmp) {
  __shared__ float cw_s[64][36];    // [c][k], padded
  __shared__ float fc1_s[128][65];  // [o][c], padded
  const int t = threadIdx.x;
  const int kt = blockIdx.x, cs = blockIdx.y;
  const int k0 = kt * 32;
  const int og = t >> 3, kg = t & 7;  // thread tile: 4 o x 4 k
  float acc[4][4] = {};
  for (int half = 0; half < 2; ++half) {
    const int cc = cs * 128 + half * 64;
    __syncthreads();
#pragma unroll
    for (int i = 0; i < 8; ++i) {
      int idx = t + 256 * i;
      int cr = idx >> 5, kk = idx & 31;
      cw_s[cr][kk] = conv_w[(cc + cr) * 3072 + k0 + kk];
    }
#pragma unroll
    for (int i = 0; i < 8; ++i) {
      int idx = t + 256 * i;
      int o = idx >> 4, c4 = (idx & 15) * 4;
      float4 v = *(const float4*)&fc1_w[o * 512 + cc + c4];
      fc1_s[o][c4 + 0] = v.x; fc1_s[o][c4 + 1] = v.y;
      fc1_s[o][c4 + 2] = v.z; fc1_s[o][c4 + 3] = v.w;
    }
    __syncthreads();
    for (int ci = 0; ci < 64; ++ci) {
      float4 cw = *(const float4*)&cw_s[ci][kg * 4];
#pragma unroll
      for (int j = 0; j < 4; ++j) {
        float fv = fc1_s[og * 4 + j][ci];
        acc[j][0] = fmaf(fv, cw.x, acc[j][0]);
        acc[j][1] = fmaf(fv, cw.y, acc[j][1]);
        acc[j][2] = fmaf(fv, cw.z, acc[j][2]);
        acc[j][3] = fmaf(fv, cw.w, acc[j][3]);
      }
    }
  }
  float* wp = Wtmp + cs * 393216;
#pragma unroll
  for (int j = 0; j < 4; ++j)
#pragma unroll
    for (int q = 0; q < 4; ++q)
      wp[(og * 4 + j) * 3072 + k0 + kg * 4 + q] = acc[j][q];
}

// ---------------- reduce 4 partials -> bf16 W ----------------
__global__ void k_cvtw(const float* __restrict__ Wtmp, __bf16* __restrict__ W) {
  int idx = blockIdx.x * 256 + threadIdx.x;
  float s = Wtmp[idx] + Wtmp[idx + 393216] + Wtmp[idx + 786432] +
            Wtmp[idx + 1179648];
  W[idx] = (__bf16)s;
}

// ---------------- main GEMM: register-streaming, no LDS/barriers/atomics ---
// grid 256 blocks x 512 threads. Block = 32 rows x 128 cols, full K=3072.
// Wave tile 16x32: A frags straight from x (fp32->bf16 in reg), B frags
// straight from W (L2-resident, 768 KB). Fused bias + row-norm epilogue.
#define PF(CC, AB, BB)                                               \
  {                                                                  \
    const float* an = ap + (CC) * 128;                               \
    const __bf16* bn0 = bp0 + (CC) * 128;                            \
    const __bf16* bn1 = bp1 + (CC) * 128;                            \
    _Pragma("unroll") for (int ks = 0; ks < 4; ++ks) {               \
      AB[ks][0] = *(const float4*)(an + ks * 32);                    \
      AB[ks][1] = *(const float4*)(an + ks * 32 + 4);                \
      BB[ks][0] = *(const uint4*)(bn0 + ks * 32);                    \
      BB[ks][1] = *(const uint4*)(bn1 + ks * 32);                    \
    }                                                                \
  }

#define COMP(AB, BB)                                                 \
  {                                                                  \
    _Pragma("unroll") for (int ks = 0; ks < 4; ++ks) {               \
      union { __bf16 h[8]; bf16x8 v; } pa;                           \
      float4 lo = AB[ks][0], hi = AB[ks][1];                         \
      pa.h[0] = (__bf16)lo.x; pa.h[1] = (__bf16)lo.y;                \
      pa.h[2] = (__bf16)lo.z; pa.h[3] = (__bf16)lo.w;                \
      pa.h[4] = (__bf16)hi.x; pa.h[5] = (__bf16)hi.y;                \
      pa.h[6] = (__bf16)hi.z; pa.h[7] = (__bf16)hi.w;                \
      acc0 = mfma16(pa.v, *(const bf16x8*)&BB[ks][0], acc0);         \
      acc1 = mfma16(pa.v, *(const bf16x8*)&BB[ks][1], acc1);         \
    }                                                                \
  }

__global__ __launch_bounds__(512) void k_gemm1(const float* __restrict__ x,
                                               const __bf16* __restrict__ W,
                                               const float* __restrict__ bias2,
                                               float* __restrict__ f,
                                               __bf16* __restrict__ fn) {
  const int t = threadIdx.x;
  const int wave = t >> 6, lane = t & 63;
  const int l15 = lane & 15, quad = lane >> 4;
  const int mhalf = wave & 1;   // row group 0/1
  const int nw = wave >> 1;     // col strip 0..3
  const int m0 = blockIdx.x * 32;
  const int arow = m0 + mhalf * 16 + l15;
  const int n0 = nw * 32;
  const float* ap = x + arow * 3072 + quad * 8;
  const __bf16* bp0 = W + (n0 + l15) * 3072 + quad * 8;
  const __bf16* bp1 = bp0 + 16 * 3072;

  f32x4 acc0 = {0.f, 0.f, 0.f, 0.f}, acc1 = {0.f, 0.f, 0.f, 0.f};
  float4 ab0[4][2], ab1[4][2];
  uint4 bb0[4][2], bb1[4][2];
  PF(0, ab0, bb0)
  for (int c = 0; c < 24; c += 2) {
    if (c + 1 < 24) PF(c + 1, ab1, bb1)
    COMP(ab0, bb0)
    if (c + 2 < 24) PF(c + 2, ab0, bb0)
    COMP(ab1, bb1)
  }

  // epilogue: bias + row L2-norm (block covers full 128 cols of 32 rows)
  __shared__ float ssq[32];
  if (t < 32) ssq[t] = 0.f;
  __syncthreads();
  float bv0 = bias2[n0 + l15], bv1 = bias2[n0 + 16 + l15];
  float v0[4], v1[4];
#pragma unroll
  for (int r = 0; r < 4; ++r) {
    v0[r] = acc0[r] + bv0;
    v1[r] = acc1[r] + bv1;
    float part = v0[r] * v0[r] + v1[r] * v1[r];
#pragma unroll
    for (int m = 1; m < 16; m <<= 1) part += __shfl_xor(part, m, 64);
    if (l15 == 0) atomicAdd(&ssq[mhalf * 16 + quad * 4 + r], part);
  }
  __syncthreads();
#pragma unroll
  for (int r = 0; r < 4; ++r) {
    int lrow = mhalf * 16 + quad * 4 + r;
    int grow = m0 + lrow;
    float inv = 1.f / fmaxf(sqrtf(ssq[lrow]), EPS);
    f[grow * 128 + n0 + l15] = v0[r];
    f[grow * 128 + n0 + 16 + l15] = v1[r];
    fn[grow * 128 + n0 + l15] = (__bf16)(v0[r] * inv);
    fn[grow * 128 + n0 + 16 + l15] = (__bf16)(v1[r] * inv);
  }
}

// ---------------- A[b] = fn_b @ fn_b^T (symmetric cosine affinity) ---------
__global__ __launch_bounds__(256) void k_gemm2(const __bf16* __restrict__ fn,
                                               float* __restrict__ Aout) {
  __shared__ __align__(16) __bf16 Li[64][136];
  __shared__ __align__(16) __bf16 Lj[64][136];
  const int t = threadIdx.x;
  const int b = blockIdx.y;
  const int ti = blockIdx.x >> 2, tj = blockIdx.x & 3;
  const int i0 = ti * 64, j0 = tj * 64;
  const int wave = t >> 6, lane = t & 63;
  const int l15 = lane & 15, quad = lane >> 4;
  const __bf16* fb = fn + b * 32768;
#pragma unroll
  for (int i = 0; i < 4; ++i) {
    int idx = t + 256 * i;
    int r = idx >> 4, c8 = (idx & 15) * 8;
    *(uint4*)&Li[r][c8] = *(const uint4*)&fb[(i0 + r) * 128 + c8];
    *(uint4*)&Lj[r][c8] = *(const uint4*)&fb[(j0 + r) * 128 + c8];
  }
  __syncthreads();
  f32x4 acc[4] = {{0.f, 0.f, 0.f, 0.f}, {0.f, 0.f, 0.f, 0.f},
                  {0.f, 0.f, 0.f, 0.f}, {0.f, 0.f, 0.f, 0.f}};
#pragma unroll
  for (int ks = 0; ks < 4; ++ks) {
    bf16x8 af = *(const bf16x8*)&Li[wave * 16 + l15][ks * 32 + quad * 8];
#pragma unroll
    for (int nt = 0; nt < 4; ++nt) {
      bf16x8 bf = *(const bf16x8*)&Lj[nt * 16 + l15][ks * 32 + quad * 8];
      acc[nt] = mfma16(af, bf, acc[nt]);
    }
  }
  float* Ab = Aout + b * 65536;
#pragma unroll
  for (int nt = 0; nt < 4; ++nt) {
    int gj = j0 + nt * 16 + l15;
#pragma unroll
    for (int r = 0; r < 4; ++r) {
      int gi = i0 + wave * 16 + quad * 4 + r;
      Ab[gi * 256 + gj] = acc[nt][r];
    }
  }
}

// ---------------- Z partials: direct write, no atomics ----------------
// Zp[0][nc][b][m] = sum over 32 rows of E*d1 ; Zp[1][..] same with d2.
__global__ __launch_bounds__(256) void k_z(const float* __restrict__ Aout,
                                           const float* __restrict__ d1,
                                           const float* __restrict__ d2,
                                           float* __restrict__ Zp) {
  const int t = threadIdx.x;  // column m
  const int b = blockIdx.y, nc = blockIdx.x;
  const int base = b * 65536;
  float z1 = 0.f, z2 = 0.f;
  for (int r = 0; r < 32; ++r) {
    int n = nc * 32 + r;
    int idx = base + n * 256 + t;
    float a = Aout[idx];
    float e = __expf(fmaf(S_SCALE, a, -S_SCALE));
    if (n != t) {
      z1 = fmaf(e, d1[idx], z1);
      z2 = fmaf(e, d2[idx], z2);
    }
  }
  Zp[nc * 8192 + b * 256 + t] = z1;
  Zp[(8 + nc) * 8192 + b * 256 + t] = z2;
}

// ---------------- loss = -1/8192 * sum E^2*d2[i,k]*d1[k,i]/(Z2[k]Z1[i]) ----
__global__ __launch_bounds__(256) void k_loss(const float* __restrict__ Aout,
                                              const float* __restrict__ d1,
                                              const float* __restrict__ d2,
                                              const float* __restrict__ Zp,
                                              float* __restrict__ loss) {
  __shared__ float d1s[64][65];  // d1[k][i] tile, transposed access
  __shared__ float z1s[64], z2s[64];
  __shared__ float red[4];
  const int t = threadIdx.x;
  const int b = blockIdx.y;
  const int ic = blockIdx.x >> 2, kc = blockIdx.x & 3;
  const int i0 = ic * 64, k0 = kc * 64;
  const int base = b * 65536;
  if (t < 64) {
    float s = 0.f;
#pragma unroll
    for (int p = 0; p < 8; ++p) s += Zp[p * 8192 + b * 256 + i0 + t];
    z1s[t] = 1.f / fmaxf(s, EPS);
  } else if (t < 128) {
    float s = 0.f;
#pragma unroll
    for (int p = 0; p < 8; ++p) s += Zp[(8 + p) * 8192 + b * 256 + k0 + t - 64];
    z2s[t - 64] = 1.f / fmaxf(s, EPS);
  }
#pragma unroll
  for (int ii = 0; ii < 16; ++ii) {
    int idx = t + 256 * ii;
    int kr = idx >> 6, ci = idx & 63;
    d1s[kr][ci] = d1[base + (k0 + kr) * 256 + i0 + ci];
  }
  __syncthreads();
  const int kl = t & 63, ig = t >> 6;
  float inv2 = z2s[kl];
  float accv = 0.f;
  for (int ii = 0; ii < 16; ++ii) {
    int il = ig * 16 + ii;
    int idx = base + (i0 + il) * 256 + k0 + kl;
    float a = Aout[idx];
    float e = __expf(fmaf(2.f * S_SCALE, a, -2.f * S_SCALE));
    float v = e * d2[idx] * d1s[kl][il] * z1s[il] * inv2;
    if (i0 + il != k0 + kl) accv += v;
  }
  accv = waveSum(accv);
  if ((t & 63) == 0) red[t >> 6] = accv;
  __syncthreads();
  if (t == 0) {
    float tot = red[0] + red[1] + red[2] + red[3];
    atomicAdd(loss, tot * (-1.f / 8192.f));
  }
}

extern "C" void kernel_launch(void* const* d_in, const int* in_sizes, int n_in,
                              void* d_out, int out_size, void* d_ws,
                              size_t ws_size, hipStream_t stream) {
  const float* x = (const float*)d_in[0];
  const float* conv_w = (const float*)d_in[1];
  const float* conv_b = (const float*)d_in[2];
  const float* fc1_w = (const float*)d_in[3];
  const float* fc1_b = (const float*)d_in[4];
  const float* drop1 = (const float*)d_in[5];
  const float* drop2 = (const float*)d_in[6];
  char* ws = (char*)d_ws;
  __bf16* W = (__bf16*)(ws + OFF_W);
  float* bias2 = (float*)(ws + OFF_BIAS);
  __bf16* fn = (__bf16*)(ws + OFF_FN);
  float* Zp = (float*)(ws + OFF_ZP);
  float* Wtmp = (float*)(ws + OFF_WTMP);
  float* f = (float*)d_out;         // [8192,128]
  float* Aout = f + 1048576;        // [32,256,256]
  float* loss = f + 3145728;        // scalar

  k_bias<<<128, 256, 0, stream>>>(fc1_w, conv_b, fc1_b, bias2, loss);
  k_fusew<<<dim3(96, 4), 256, 0, stream>>>(conv_w, fc1_w, Wtmp);
  k_cvtw<<<1536, 256, 0, stream>>>(Wtmp, W);
  k_gemm1<<<256, 512, 0, stream>>>(x, W, bias2, f, fn);
  k_gemm2<<<dim3(16, 32), 256, 0, stream>>>(fn, Aout);
  k_z<<<dim3(8, 32), 256, 0, stream>>>(Aout, drop1, drop2, Zp);
  k_loss<<<dim3(16, 32), 256, 0, stream>>>(Aout, drop1, drop2, Zp, loss);
}

// Round 4
// 238.480 us; speedup vs baseline: 1.3281x; 1.1983x over previous
//
#include <hip/hip_runtime.h>
#include <stdint.h>

#define S_SCALE 11.313708498984761f
#define EPS 1e-12f

typedef __bf16 bf16x8 __attribute__((ext_vector_type(8)));
typedef float  f32x4  __attribute__((ext_vector_type(4)));

__device__ __forceinline__ f32x4 mfma16(bf16x8 a, bf16x8 b, f32x4 c) {
  return __builtin_amdgcn_mfma_f32_16x16x32_bf16(a, b, c, 0, 0, 0);
}

__device__ __forceinline__ float waveSum(float v) {
#pragma unroll
  for (int m = 32; m > 0; m >>= 1) v += __shfl_xor(v, m, 64);
  return v;
}

// async global->LDS DMA, 16B per lane, LDS dest = uniform base + lane*16
__device__ __forceinline__ void load_lds16(const float* g, float* l) {
  __builtin_amdgcn_global_load_lds(
      (const __attribute__((address_space(1))) uint32_t*)g,
      (__attribute__((address_space(3))) uint32_t*)l, 16, 0, 0);
}

// ---- ws layout (byte offsets) ----
// W bf16 [128][3072]       : [0, 786432)
// bias2 f32 [128]          : [786432, 786944)
// fn bf16 [8192][128]      : [786944, 2884096)
// Zp f32 [2][4][32][256]   : [2884096, 3146240)
// P1 f32 [8192][128]       : [3146240, 7340544)
#define OFF_W    0
#define OFF_BIAS 786432
#define OFF_FN   786944
#define OFF_ZP   2884096
#define OFF_P1   3146240

// ---------------- fused bias: bias2[o] = fc1_w[o,:] . conv_b + fc1_b[o] ----
// also zeroes the loss accumulator (runs first on the stream).
__global__ __launch_bounds__(256) void k_bias(const float* __restrict__ fc1_w,
                                              const float* __restrict__ conv_b,
                                              const float* __restrict__ fc1_b,
                                              float* __restrict__ bias2,
                                              float* __restrict__ loss) {
  const int o = blockIdx.x, t = threadIdx.x;
  if (o == 0 && t == 0) loss[0] = 0.f;
  float p = fc1_w[o * 512 + t] * conv_b[t] +
            fc1_w[o * 512 + 256 + t] * conv_b[256 + t];
  p = waveSum(p);
  __shared__ float red[4];
  if ((t & 63) == 0) red[t >> 6] = p;
  __syncthreads();
  if (t == 0) bias2[o] = red[0] + red[1] + red[2] + red[3] + fc1_b[o];
}

// ---------------- fused weight, single pass: W[o][k] = sum_c fc1*conv_w ----
// grid 96 (k-chunks of 32), 256 thr. Accumulate all 512 c in regs, write bf16.
__global__ __launch_bounds__(256) void k_fusew2(const float* __restrict__ conv_w,
                                                const float* __restrict__ fc1_w,
                                                __bf16* __restrict__ W) {
  __shared__ float cw_s[64][36];    // [c][k], padded
  __shared__ float fc1_s[128][65];  // [o][c], padded
  const int t = threadIdx.x;
  const int kt = blockIdx.x;
  const int k0 = kt * 32;
  const int og = t >> 3, kg = t & 7;  // thread tile: 4 o x 4 k
  float acc[4][4] = {};
  for (int cs = 0; cs < 8; ++cs) {
    const int cc = cs * 64;
    __syncthreads();
#pragma unroll
    for (int i = 0; i < 8; ++i) {
      int idx = t + 256 * i;
      int cr = idx >> 5, kk = idx & 31;
      cw_s[cr][kk] = conv_w[(cc + cr) * 3072 + k0 + kk];
    }
#pragma unroll
    for (int i = 0; i < 8; ++i) {
      int idx = t + 256 * i;
      int o = idx >> 4, c4 = (idx & 15) * 4;
      float4 v = *(const float4*)&fc1_w[o * 512 + cc + c4];
      fc1_s[o][c4 + 0] = v.x; fc1_s[o][c4 + 1] = v.y;
      fc1_s[o][c4 + 2] = v.z; fc1_s[o][c4 + 3] = v.w;
    }
    __syncthreads();
    for (int ci = 0; ci < 64; ++ci) {
      float4 cw = *(const float4*)&cw_s[ci][kg * 4];
#pragma unroll
      for (int j = 0; j < 4; ++j) {
        float fv = fc1_s[og * 4 + j][ci];
        acc[j][0] = fmaf(fv, cw.x, acc[j][0]);
        acc[j][1] = fmaf(fv, cw.y, acc[j][1]);
        acc[j][2] = fmaf(fv, cw.z, acc[j][2]);
        acc[j][3] = fmaf(fv, cw.w, acc[j][3]);
      }
    }
  }
#pragma unroll
  for (int j = 0; j < 4; ++j)
#pragma unroll
    for (int q = 0; q < 4; ++q)
      W[(og * 4 + j) * 3072 + k0 + kg * 4 + q] = (__bf16)acc[j][q];
}

// ---------------- main GEMM: global_load_lds A, B from L2, split-K=2 -------
// grid (256, 2) x 256 thr. Block = 32 rows x 128 cols x K=1536 (24 iters BK=64).
// A LDS is XOR-swizzled in 16B chunks: phys_chunk = log_chunk ^ (row&15).
__global__ __launch_bounds__(256) void k_gemm1(const float* __restrict__ x,
                                               const __bf16* __restrict__ W,
                                               float* __restrict__ P0,
                                               float* __restrict__ P1) {
  __shared__ __align__(16) float A_lds[32 * 64];  // 8 KB
  const int t = threadIdx.x;
  const int wave = t >> 6, lane = t & 63;
  const int l15 = lane & 15, quad = lane >> 4;
  const int m0 = blockIdx.x * 32;
  const int kbase = blockIdx.y * 1536;
  float* P = blockIdx.y ? P1 : P0;

  // DMA source mapping (2 insts/wave): inst jj=wave*2+j covers LDS fp32
  // [jj*256 + lane*4 ..+3] -> row = jj*4 + lane/16, phys chunk cp = lane%16,
  // logical chunk cl = cp ^ (row&15), global col = cl*4.
  int dr[2], dc[2];
#pragma unroll
  for (int j = 0; j < 2; ++j) {
    int row = wave * 8 + j * 4 + (lane >> 4);
    int cl = (lane & 15) ^ (row & 15);
    dr[j] = row;
    dc[j] = cl * 4;
  }

  f32x4 acc[2][2] = {{{0.f,0.f,0.f,0.f},{0.f,0.f,0.f,0.f}},
                     {{0.f,0.f,0.f,0.f},{0.f,0.f,0.f,0.f}}};
  const __bf16* bp = W + (wave * 32 + l15) * 3072 + quad * 8;

  for (int it = 0; it < 24; ++it) {
    const int k0 = kbase + it * 64;
    __syncthreads();  // previous iter's LDS reads done
#pragma unroll
    for (int j = 0; j < 2; ++j)
      load_lds16(x + (m0 + dr[j]) * 3072 + k0 + dc[j],
                 &A_lds[(wave * 2 + j) * 256]);
    uint4 breg[2][2];
#pragma unroll
    for (int ks = 0; ks < 2; ++ks)
#pragma unroll
      for (int ni = 0; ni < 2; ++ni)
        breg[ks][ni] = *(const uint4*)(bp + ni * 16 * 3072 + k0 + ks * 32);
    __syncthreads();  // vmcnt(0) drain: A in LDS, B in regs
#pragma unroll
    for (int ks = 0; ks < 2; ++ks) {
      bf16x8 afrag[2];
#pragma unroll
      for (int mi = 0; mi < 2; ++mi) {
        const int rb = (l15 + mi * 16) * 64;
        float4 lo = *(const float4*)&A_lds[rb + (((ks * 8 + quad * 2 + 0) ^ l15) << 2)];
        float4 hi = *(const float4*)&A_lds[rb + (((ks * 8 + quad * 2 + 1) ^ l15) << 2)];
        union { __bf16 h[8]; bf16x8 v; } pk;
        pk.h[0] = (__bf16)lo.x; pk.h[1] = (__bf16)lo.y;
        pk.h[2] = (__bf16)lo.z; pk.h[3] = (__bf16)lo.w;
        pk.h[4] = (__bf16)hi.x; pk.h[5] = (__bf16)hi.y;
        pk.h[6] = (__bf16)hi.z; pk.h[7] = (__bf16)hi.w;
        afrag[mi] = pk.v;
      }
#pragma unroll
      for (int mi = 0; mi < 2; ++mi)
#pragma unroll
        for (int ni = 0; ni < 2; ++ni)
          acc[mi][ni] = mfma16(afrag[mi], *(const bf16x8*)&breg[ks][ni],
                               acc[mi][ni]);
    }
  }
#pragma unroll
  for (int mi = 0; mi < 2; ++mi)
#pragma unroll
    for (int ni = 0; ni < 2; ++ni) {
      int col = wave * 32 + ni * 16 + l15;
#pragma unroll
      for (int r = 0; r < 4; ++r) {
        int row = m0 + mi * 16 + quad * 4 + r;
        P[row * 128 + col] = acc[mi][ni][r];
      }
    }
}

// ---------------- finalize: f = P0+P1+bias, row L2-norm -> fn bf16 ---------
// grid 2048 x 256: wave handles one row; f is read (P0) and rewritten in place.
__global__ __launch_bounds__(256) void k_fin(float* __restrict__ f_inout,
                                             const float* __restrict__ P1,
                                             const float* __restrict__ bias2,
                                             __bf16* __restrict__ fn) {
  const int wave = threadIdx.x >> 6, lane = threadIdx.x & 63;
  const int row = blockIdx.x * 4 + wave;
  const int i0 = row * 128 + lane, i1 = i0 + 64;
  float v0 = f_inout[i0] + P1[i0] + bias2[lane];
  float v1 = f_inout[i1] + P1[i1] + bias2[lane + 64];
  float ss = waveSum(fmaf(v0, v0, v1 * v1));
  float inv = 1.f / fmaxf(sqrtf(ss), EPS);
  f_inout[i0] = v0;
  f_inout[i1] = v1;
  fn[i0] = (__bf16)(v0 * inv);
  fn[i1] = (__bf16)(v1 * inv);
}

// ---------------- A[b] = fn_b @ fn_b^T  +  fused Z column-partials ---------
// Zp[z][ti][b][m]: partial (over 64 rows of ti) column sums of E*(1-eye)*drop.
__global__ __launch_bounds__(256) void k_gemm2(const __bf16* __restrict__ fn,
                                               const float* __restrict__ d1,
                                               const float* __restrict__ d2,
                                               float* __restrict__ Aout,
                                               float* __restrict__ Zp) {
  __shared__ __align__(16) __bf16 Li[64][136];
  __shared__ __align__(16) __bf16 Lj[64][136];
  __shared__ float zred[2][4][64];
  const int t = threadIdx.x;
  const int b = blockIdx.y;
  const int ti = blockIdx.x >> 2, tj = blockIdx.x & 3;
  const int i0 = ti * 64, j0 = tj * 64;
  const int wave = t >> 6, lane = t & 63;
  const int l15 = lane & 15, quad = lane >> 4;
  const __bf16* fb = fn + b * 32768;
#pragma unroll
  for (int i = 0; i < 4; ++i) {
    int idx = t + 256 * i;
    int r = idx >> 4, c8 = (idx & 15) * 8;
    *(uint4*)&Li[r][c8] = *(const uint4*)&fb[(i0 + r) * 128 + c8];
    *(uint4*)&Lj[r][c8] = *(const uint4*)&fb[(j0 + r) * 128 + c8];
  }
  __syncthreads();
  f32x4 acc[4] = {{0.f, 0.f, 0.f, 0.f}, {0.f, 0.f, 0.f, 0.f},
                  {0.f, 0.f, 0.f, 0.f}, {0.f, 0.f, 0.f, 0.f}};
#pragma unroll
  for (int ks = 0; ks < 4; ++ks) {
    bf16x8 af = *(const bf16x8*)&Li[wave * 16 + l15][ks * 32 + quad * 8];
#pragma unroll
    for (int nt = 0; nt < 4; ++nt) {
      bf16x8 bf = *(const bf16x8*)&Lj[nt * 16 + l15][ks * 32 + quad * 8];
      acc[nt] = mfma16(af, bf, acc[nt]);
    }
  }
  const int base = b * 65536;
  float* Ab = Aout + base;
  float z1c[4] = {0.f, 0.f, 0.f, 0.f}, z2c[4] = {0.f, 0.f, 0.f, 0.f};
#pragma unroll
  for (int nt = 0; nt < 4; ++nt) {
    int gj = j0 + nt * 16 + l15;
#pragma unroll
    for (int r = 0; r < 4; ++r) {
      int gi = i0 + wave * 16 + quad * 4 + r;
      float a = acc[nt][r];
      Ab[gi * 256 + gj] = a;
      float e = __expf(fmaf(S_SCALE, a, -S_SCALE));
      if (gi != gj) {
        int idx = base + gi * 256 + gj;
        z1c[nt] = fmaf(e, d1[idx], z1c[nt]);
        z2c[nt] = fmaf(e, d2[idx], z2c[nt]);
      }
    }
  }
#pragma unroll
  for (int nt = 0; nt < 4; ++nt) {
    z1c[nt] += __shfl_xor(z1c[nt], 16, 64);
    z1c[nt] += __shfl_xor(z1c[nt], 32, 64);
    z2c[nt] += __shfl_xor(z2c[nt], 16, 64);
    z2c[nt] += __shfl_xor(z2c[nt], 32, 64);
  }
  if (quad == 0) {
#pragma unroll
    for (int nt = 0; nt < 4; ++nt) {
      zred[0][wave][nt * 16 + l15] = z1c[nt];
      zred[1][wave][nt * 16 + l15] = z2c[nt];
    }
  }
  __syncthreads();
  if (t < 128) {
    int z = t >> 6, c = t & 63;
    float s = zred[z][0][c] + zred[z][1][c] + zred[z][2][c] + zred[z][3][c];
    Zp[(z * 4 + ti) * 8192 + b * 256 + j0 + c] = s;
  }
}

// ---------------- loss = -1/8192 * sum E^2*d2[i,k]*d1[k,i]/(Z2[k]Z1[i]) ----
__global__ __launch_bounds__(256) void k_loss(const float* __restrict__ Aout,
                                              const float* __restrict__ d1,
                                              const float* __restrict__ d2,
                                              const float* __restrict__ Zp,
                                              float* __restrict__ loss) {
  __shared__ float d1s[64][65];  // d1[k][i] tile, transposed access
  __shared__ float z1s[64], z2s[64];
  __shared__ float red[4];
  const int t = threadIdx.x;
  const int b = blockIdx.y;
  const int ic = blockIdx.x >> 2, kc = blockIdx.x & 3;
  const int i0 = ic * 64, k0 = kc * 64;
  const int base = b * 65536;
  if (t < 64) {
    float s = 0.f;
#pragma unroll
    for (int p = 0; p < 4; ++p) s += Zp[p * 8192 + b * 256 + i0 + t];
    z1s[t] = 1.f / fmaxf(s, EPS);
  } else if (t < 128) {
    float s = 0.f;
#pragma unroll
    for (int p = 0; p < 4; ++p) s += Zp[(4 + p) * 8192 + b * 256 + k0 + t - 64];
    z2s[t - 64] = 1.f / fmaxf(s, EPS);
  }
#pragma unroll
  for (int ii = 0; ii < 16; ++ii) {
    int idx = t + 256 * ii;
    int kr = idx >> 6, ci = idx & 63;
    d1s[kr][ci] = d1[base + (k0 + kr) * 256 + i0 + ci];
  }
  __syncthreads();
  const int kl = t & 63, ig = t >> 6;
  float inv2 = z2s[kl];
  float accv = 0.f;
  for (int ii = 0; ii < 16; ++ii) {
    int il = ig * 16 + ii;
    int idx = base + (i0 + il) * 256 + k0 + kl;
    float a = Aout[idx];
    float e = __expf(fmaf(2.f * S_SCALE, a, -2.f * S_SCALE));
    float v = e * d2[idx] * d1s[kl][il] * z1s[il] * inv2;
    if (i0 + il != k0 + kl) accv += v;
  }
  accv = waveSum(accv);
  if ((t & 63) == 0) red[t >> 6] = accv;
  __syncthreads();
  if (t == 0) {
    float tot = red[0] + red[1] + red[2] + red[3];
    atomicAdd(loss, tot * (-1.f / 8192.f));
  }
}

extern "C" void kernel_launch(void* const* d_in, const int* in_sizes, int n_in,
                              void* d_out, int out_size, void* d_ws,
                              size_t ws_size, hipStream_t stream) {
  const float* x = (const float*)d_in[0];
  const float* conv_w = (const float*)d_in[1];
  const float* conv_b = (const float*)d_in[2];
  const float* fc1_w = (const float*)d_in[3];
  const float* fc1_b = (const float*)d_in[4];
  const float* drop1 = (const float*)d_in[5];
  const float* drop2 = (const float*)d_in[6];
  char* ws = (char*)d_ws;
  __bf16* W = (__bf16*)(ws + OFF_W);
  float* bias2 = (float*)(ws + OFF_BIAS);
  __bf16* fn = (__bf16*)(ws + OFF_FN);
  float* Zp = (float*)(ws + OFF_ZP);
  float* P1 = (float*)(ws + OFF_P1);
  float* f = (float*)d_out;         // [8192,128]  (doubles as P0)
  float* Aout = f + 1048576;        // [32,256,256]
  float* loss = f + 3145728;        // scalar

  k_bias<<<128, 256, 0, stream>>>(fc1_w, conv_b, fc1_b, bias2, loss);
  k_fusew2<<<96, 256, 0, stream>>>(conv_w, fc1_w, W);
  k_gemm1<<<dim3(256, 2), 256, 0, stream>>>(x, W, f, P1);
  k_fin<<<2048, 256, 0, stream>>>(f, P1, bias2, fn);
  k_gemm2<<<dim3(16, 32), 256, 0, stream>>>(fn, drop1, drop2, Aout, Zp);
  k_loss<<<dim3(16, 32), 256, 0, stream>>>(Aout, drop1, drop2, Zp, loss);
}